// Round 1
// baseline (254.017 us; speedup 1.0000x reference)
//
#include <hip/hip_runtime.h>
#include <float.h>

#define DIM      512
#define NCLS     21
#define MARGIN_V 5.0f
#define ROWS_PB  64            // rows per block == threads per block (1 wave)
#define DC       32            // d-chunk (floats) staged per iteration
#define NSTAGE   (DIM / DC)    // 16
#define LPAD     (DC + 1)      // padded LDS row stride (odd -> conflict-free b32)

// Kernel 1: halfc2[c] = 0.5 * ||centers[c]||^2  -> d_ws
__global__ __launch_bounds__(64)
void center_norm_kernel(const float* __restrict__ centers,
                        float* __restrict__ halfc2) {
    const int c = blockIdx.x;
    const int t = threadIdx.x;
    float s = 0.f;
#pragma unroll
    for (int i = 0; i < DIM / 64; ++i) {
        float v = centers[c * DIM + i * 64 + t];
        s = fmaf(v, v, s);
    }
#pragma unroll
    for (int off = 32; off > 0; off >>= 1)
        s += __shfl_down(s, off, 64);
    if (t == 0) halfc2[c] = 0.5f * s;
}

// Kernel 2: per-row 21 dots + margin epilogue + mean reduce
__global__ __launch_bounds__(64)
void tcl_main_kernel(const float* __restrict__ feat,
                     const float* __restrict__ centers,
                     const int* __restrict__ labels,
                     const float* __restrict__ halfc2,
                     float* __restrict__ out) {
    __shared__ float tile[ROWS_PB * LPAD];   // 64 x 33 floats = 8448 B
    const int t    = threadIdx.x;
    const int row0 = blockIdx.x * ROWS_PB;

    const int lab = labels[row0 + t];

    float acc[NCLS];
#pragma unroll
    for (int c = 0; c < NCLS; ++c) acc[c] = 0.f;

    const float4* fbase = reinterpret_cast<const float4*>(feat);

    // Stage layout: per stage the block loads 64 rows x 32 floats = 512 float4.
    // Lane t takes float4 index f = i*64 + t -> row = f>>3, j4 = f&7.
    // Consecutive lanes hit consecutive float4s: 8 rows x 128 B contiguous,
    // full 64-B lines, fully consumed -> no over-fetch.
    float4 pre[8];
#pragma unroll
    for (int i = 0; i < 8; ++i) {
        int f = i * 64 + t;
        int row = f >> 3, j4 = f & 7;
        pre[i] = fbase[(size_t)(row0 + row) * (DIM / 4) + j4];  // stage 0
    }

#pragma unroll 1
    for (int s = 0; s < NSTAGE; ++s) {
        __syncthreads();
        // write prefetched stage into padded LDS tile (b32, ~2-way max conflicts)
#pragma unroll
        for (int i = 0; i < 8; ++i) {
            int f = i * 64 + t;
            int row = f >> 3, j4 = f & 7;
            int base = row * LPAD + j4 * 4;
            tile[base + 0] = pre[i].x;
            tile[base + 1] = pre[i].y;
            tile[base + 2] = pre[i].z;
            tile[base + 3] = pre[i].w;
        }
        __syncthreads();
        // issue next stage's global loads now; consumed ~1300 cycles later
        if (s + 1 < NSTAGE) {
#pragma unroll
            for (int i = 0; i < 8; ++i) {
                int f = i * 64 + t;
                int row = f >> 3, j4 = f & 7;
                pre[i] = fbase[(size_t)(row0 + row) * (DIM / 4)
                               + (size_t)(s + 1) * (DC / 4) + j4];
            }
        }
        // compute: lane t owns row t; center reads are wave-uniform -> s_load
        const int dbase = s * DC;
#pragma unroll 2
        for (int jj = 0; jj < DC; jj += 4) {
            float f0 = tile[t * LPAD + jj + 0];
            float f1 = tile[t * LPAD + jj + 1];
            float f2 = tile[t * LPAD + jj + 2];
            float f3 = tile[t * LPAD + jj + 3];
#pragma unroll
            for (int c = 0; c < NCLS; ++c) {
                const float* cp = &centers[c * DIM + dbase + jj];
                acc[c] = fmaf(f0, cp[0],
                          fmaf(f1, cp[1],
                           fmaf(f2, cp[2],
                            fmaf(f3, cp[3], acc[c]))));
            }
        }
    }

    // epilogue: e[c] = 0.5||c||^2 - dot ; pos = e[lab]; neg = min_{c!=lab} e[c]
    float pos = 0.f, neg = FLT_MAX;
#pragma unroll
    for (int c = 0; c < NCLS; ++c) {
        float e = halfc2[c] - acc[c];
        pos = (c == lab) ? e : pos;
        neg = (c == lab) ? neg : fminf(neg, e);
    }
    float v = fmaxf(pos + MARGIN_V - neg, 0.f);

    // wave reduce (64 lanes), then one atomic per block
#pragma unroll
    for (int off = 32; off > 0; off >>= 1)
        v += __shfl_down(v, off, 64);
    if (t == 0) atomicAdd(out, v * (1.0f / 65536.f));
}

extern "C" void kernel_launch(void* const* d_in, const int* in_sizes, int n_in,
                              void* d_out, int out_size, void* d_ws, size_t ws_size,
                              hipStream_t stream) {
    const float* feat    = (const float*)d_in[0];   // (65536, 512) fp32
    const float* centers = (const float*)d_in[1];   // (21, 512) fp32
    const int*   labels  = (const int*)d_in[2];     // (65536,) int
    float* out    = (float*)d_out;                  // scalar loss
    float* halfc2 = (float*)d_ws;                   // 21 floats scratch

    hipMemsetAsync(d_out, 0, (size_t)out_size * sizeof(float), stream);
    center_norm_kernel<<<NCLS, 64, 0, stream>>>(centers, halfc2);

    const int nblocks = 65536 / ROWS_PB;            // 1024 single-wave blocks
    tcl_main_kernel<<<nblocks, 64, 0, stream>>>(feat, centers, labels, halfc2, out);
}